// Round 1
// baseline (240.053 us; speedup 1.0000x reference)
//
#include <hip/hip_runtime.h>

typedef __attribute__((ext_vector_type(8))) short bf16x8;
typedef __attribute__((ext_vector_type(4))) float f32x4;

#define BK 32

__device__ __forceinline__ ushort f2bf(float f) {
    unsigned u = __float_as_uint(f);
    unsigned r = (u + 0x7FFFu + ((u >> 16) & 1u)) >> 16;
    return (ushort)r;
}
__device__ __forceinline__ float bf2f(ushort s) {
    return __uint_as_float(((unsigned)s) << 16);
}

// ---------------------------------------------------------------------------
// Kernel 1: QKV projection. Y = X @ W^T  (X fp32 [8192][1024], W fp32 [1024][1024]
// row-major N x K i.e. "B^T" layout). Output bf16. blockIdx.z selects weight.
// 128x128 tile, BK=32, 4 waves (2x2 of 64x64), mfma_f32_16x16x32_bf16.
// ---------------------------------------------------------------------------
__global__ __launch_bounds__(256) void qkv_gemm(
    const float* __restrict__ x,
    const float* __restrict__ W0, const float* __restrict__ W1, const float* __restrict__ W2,
    ushort* __restrict__ Y0, ushort* __restrict__ Y1, ushort* __restrict__ Y2)
{
    const float* W = (blockIdx.z == 0) ? W0 : (blockIdx.z == 1) ? W1 : W2;
    ushort*     Y = (blockIdx.z == 0) ? Y0 : (blockIdx.z == 1) ? Y1 : Y2;
    const int mbase = blockIdx.x * 128;
    const int nbase = blockIdx.y * 128;

    __shared__ ushort As[128][BK];
    __shared__ ushort Bs[128][BK];

    const int tid  = threadIdx.x;
    const int lane = tid & 63, wid = tid >> 6;
    const int wr = wid >> 1, wc = wid & 1;
    const int lrow = lane & 15, kgrp = lane >> 4;

    const int srow = tid >> 1;          // 0..127
    const int scol = (tid & 1) * 16;    // 0 or 16

    f32x4 acc[4][4];
#pragma unroll
    for (int m = 0; m < 4; ++m)
#pragma unroll
        for (int n = 0; n < 4; ++n) acc[m][n] = (f32x4){0.f, 0.f, 0.f, 0.f};

    for (int kt = 0; kt < 1024 / BK; ++kt) {
        const int k0 = kt * BK;
        float4 av[4], bv[4];
#pragma unroll
        for (int q = 0; q < 4; ++q) {
            av[q] = *(const float4*)&x[(size_t)(mbase + srow) * 1024 + k0 + scol + 4 * q];
            bv[q] = *(const float4*)&W[(size_t)(nbase + srow) * 1024 + k0 + scol + 4 * q];
        }
        __syncthreads();
        {
            ushort pa[16], pb[16];
#pragma unroll
            for (int q = 0; q < 4; ++q) {
                pa[4*q+0] = f2bf(av[q].x); pa[4*q+1] = f2bf(av[q].y);
                pa[4*q+2] = f2bf(av[q].z); pa[4*q+3] = f2bf(av[q].w);
                pb[4*q+0] = f2bf(bv[q].x); pb[4*q+1] = f2bf(bv[q].y);
                pb[4*q+2] = f2bf(bv[q].z); pb[4*q+3] = f2bf(bv[q].w);
            }
            *(uint4*)&As[srow][scol]     = *(uint4*)&pa[0];
            *(uint4*)&As[srow][scol + 8] = *(uint4*)&pa[8];
            *(uint4*)&Bs[srow][scol]     = *(uint4*)&pb[0];
            *(uint4*)&Bs[srow][scol + 8] = *(uint4*)&pb[8];
        }
        __syncthreads();

        bf16x8 af[4], bf[4];
#pragma unroll
        for (int m = 0; m < 4; ++m)
            af[m] = *(const bf16x8*)&As[wr * 64 + m * 16 + lrow][kgrp * 8];
#pragma unroll
        for (int n = 0; n < 4; ++n)
            bf[n] = *(const bf16x8*)&Bs[wc * 64 + n * 16 + lrow][kgrp * 8];
#pragma unroll
        for (int m = 0; m < 4; ++m)
#pragma unroll
            for (int n = 0; n < 4; ++n)
                acc[m][n] = __builtin_amdgcn_mfma_f32_16x16x32_bf16(af[m], bf[n], acc[m][n], 0, 0, 0);
    }

#pragma unroll
    for (int m = 0; m < 4; ++m)
#pragma unroll
        for (int n = 0; n < 4; ++n)
#pragma unroll
            for (int r = 0; r < 4; ++r) {
                int gr = mbase + wr * 64 + m * 16 + kgrp * 4 + r;
                int gc = nbase + wc * 64 + n * 16 + lrow;
                Y[(size_t)gr * 1024 + gc] = f2bf(acc[m][n][r]);
            }
}

// ---------------------------------------------------------------------------
// Kernel 2: scores S = (Q @ K^T) * 1/32, lower-triangular 128x128 tiles only.
// Q,K bf16 [2048][1024] per batch. S bf16 [2048][2048] per batch.
// blockIdx.x = triangular tile index (136), blockIdx.y = batch.
// ---------------------------------------------------------------------------
__global__ __launch_bounds__(256) void scores_gemm(
    const ushort* __restrict__ Qall, const ushort* __restrict__ Kall,
    ushort* __restrict__ Sall)
{
    const ushort* Q = Qall + (size_t)blockIdx.y * 2048 * 1024;
    const ushort* K = Kall + (size_t)blockIdx.y * 2048 * 1024;
    ushort*       S = Sall + (size_t)blockIdx.y * 2048 * 2048;

    int t = blockIdx.x;
    int it = (int)((sqrtf(8.0f * (float)t + 1.0f) - 1.0f) * 0.5f);
    while ((it + 1) * (it + 2) / 2 <= t) ++it;
    while (it * (it + 1) / 2 > t) --it;
    int jt = t - it * (it + 1) / 2;
    const int ibase = it * 128, jbase = jt * 128;

    __shared__ ushort As[128][BK];
    __shared__ ushort Bs[128][BK];

    const int tid  = threadIdx.x;
    const int lane = tid & 63, wid = tid >> 6;
    const int wr = wid >> 1, wc = wid & 1;
    const int lrow = lane & 15, kgrp = lane >> 4;
    const int srow = tid >> 1;
    const int scol = (tid & 1) * 16;

    f32x4 acc[4][4];
#pragma unroll
    for (int m = 0; m < 4; ++m)
#pragma unroll
        for (int n = 0; n < 4; ++n) acc[m][n] = (f32x4){0.f, 0.f, 0.f, 0.f};

    for (int kt = 0; kt < 1024 / BK; ++kt) {
        const int k0 = kt * BK;
        uint4 a0 = *(const uint4*)&Q[(size_t)(ibase + srow) * 1024 + k0 + scol];
        uint4 a1 = *(const uint4*)&Q[(size_t)(ibase + srow) * 1024 + k0 + scol + 8];
        uint4 b0 = *(const uint4*)&K[(size_t)(jbase + srow) * 1024 + k0 + scol];
        uint4 b1 = *(const uint4*)&K[(size_t)(jbase + srow) * 1024 + k0 + scol + 8];
        __syncthreads();
        *(uint4*)&As[srow][scol]     = a0;
        *(uint4*)&As[srow][scol + 8] = a1;
        *(uint4*)&Bs[srow][scol]     = b0;
        *(uint4*)&Bs[srow][scol + 8] = b1;
        __syncthreads();

        bf16x8 af[4], bf[4];
#pragma unroll
        for (int m = 0; m < 4; ++m)
            af[m] = *(const bf16x8*)&As[wr * 64 + m * 16 + lrow][kgrp * 8];
#pragma unroll
        for (int n = 0; n < 4; ++n)
            bf[n] = *(const bf16x8*)&Bs[wc * 64 + n * 16 + lrow][kgrp * 8];
#pragma unroll
        for (int m = 0; m < 4; ++m)
#pragma unroll
            for (int n = 0; n < 4; ++n)
                acc[m][n] = __builtin_amdgcn_mfma_f32_16x16x32_bf16(af[m], bf[n], acc[m][n], 0, 0, 0);
    }

#pragma unroll
    for (int m = 0; m < 4; ++m)
#pragma unroll
        for (int n = 0; n < 4; ++n)
#pragma unroll
            for (int r = 0; r < 4; ++r) {
                int gi = ibase + wr * 64 + m * 16 + kgrp * 4 + r;
                int gj = jbase + wc * 64 + n * 16 + lrow;
                S[(size_t)gi * 2048 + gj] = f2bf(acc[m][n][r] * 0.03125f);
            }
}

// ---------------------------------------------------------------------------
// Kernel 3: causal row softmax in place on bf16 S. One block per row.
// Writes zeros for j > i (so PV can read dense tiles).
// ---------------------------------------------------------------------------
__global__ __launch_bounds__(256) void softmax_rows(ushort* __restrict__ Sall)
{
    ushort* S = Sall + (size_t)blockIdx.y * 2048 * 2048;
    const int i   = blockIdx.x;
    const int tid = threadIdx.x;
    const int j0  = tid * 8;

    union { uint4 v; ushort u[8]; } pk;
    pk.v = *(const uint4*)&S[(size_t)i * 2048 + j0];

    float f[8];
    float mx = -INFINITY;
#pragma unroll
    for (int e = 0; e < 8; ++e) {
        float v = (j0 + e <= i) ? bf2f(pk.u[e]) : -INFINITY;
        f[e] = v;
        mx = fmaxf(mx, v);
    }
    // block-wide max (256 threads = 4 waves)
#pragma unroll
    for (int off = 1; off < 64; off <<= 1) mx = fmaxf(mx, __shfl_xor(mx, off));
    __shared__ float redm[4];
    if ((tid & 63) == 0) redm[tid >> 6] = mx;
    __syncthreads();
    mx = fmaxf(fmaxf(redm[0], redm[1]), fmaxf(redm[2], redm[3]));

    float s = 0.f;
#pragma unroll
    for (int e = 0; e < 8; ++e) {
        float p = __expf(f[e] - mx);   // exp(-inf - m) = 0
        f[e] = p;
        s += p;
    }
#pragma unroll
    for (int off = 1; off < 64; off <<= 1) s += __shfl_xor(s, off);
    __shared__ float reds[4];
    if ((tid & 63) == 0) reds[tid >> 6] = s;
    __syncthreads();
    s = reds[0] + reds[1] + reds[2] + reds[3];

    const float inv = 1.0f / s;
#pragma unroll
    for (int e = 0; e < 8; ++e) pk.u[e] = f2bf(f[e] * inv);
    *(uint4*)&S[(size_t)i * 2048 + j0] = pk.v;
}

// ---------------------------------------------------------------------------
// Kernel 4: V transpose per batch: V [2048][1024] -> Vt [1024][2048] (bf16).
// ---------------------------------------------------------------------------
__global__ void transpose_v(const ushort* __restrict__ Vall, ushort* __restrict__ Vtall)
{
    const ushort* V  = Vall  + (size_t)blockIdx.z * 2048 * 1024;
    ushort*       Vt = Vtall + (size_t)blockIdx.z * 1024 * 2048;
    __shared__ ushort t[32][33];
    const int s0 = blockIdx.x * 32, d0 = blockIdx.y * 32;
    t[threadIdx.y][threadIdx.x] = V[(size_t)(s0 + threadIdx.y) * 1024 + d0 + threadIdx.x];
    __syncthreads();
    Vt[(size_t)(d0 + threadIdx.y) * 2048 + s0 + threadIdx.x] = t[threadIdx.x][threadIdx.y];
}

// ---------------------------------------------------------------------------
// Kernel 5: O = P @ V. P bf16 [2048][2048] (rows zero beyond diagonal),
// Vt bf16 [1024][2048] (B^T layout). Output fp32 [2048][1024].
// K-loop truncated at the causal diagonal.
// ---------------------------------------------------------------------------
__global__ __launch_bounds__(256) void pv_gemm(
    const ushort* __restrict__ Pall, const ushort* __restrict__ Vtall,
    float* __restrict__ Oall)
{
    const ushort* P  = Pall  + (size_t)blockIdx.z * 2048 * 2048;
    const ushort* Vt = Vtall + (size_t)blockIdx.z * 1024 * 2048;
    float*        O  = Oall  + (size_t)blockIdx.z * 2048 * 1024;

    const int it = blockIdx.x;          // 0..15
    const int ibase = it * 128;
    const int nbase = blockIdx.y * 128;
    const int KT = 4 * (it + 1);        // k-tiles up to the diagonal

    __shared__ ushort As[128][BK];
    __shared__ ushort Bs[128][BK];

    const int tid  = threadIdx.x;
    const int lane = tid & 63, wid = tid >> 6;
    const int wr = wid >> 1, wc = wid & 1;
    const int lrow = lane & 15, kgrp = lane >> 4;
    const int srow = tid >> 1;
    const int scol = (tid & 1) * 16;

    f32x4 acc[4][4];
#pragma unroll
    for (int m = 0; m < 4; ++m)
#pragma unroll
        for (int n = 0; n < 4; ++n) acc[m][n] = (f32x4){0.f, 0.f, 0.f, 0.f};

    for (int kt = 0; kt < KT; ++kt) {
        const int k0 = kt * BK;
        uint4 a0 = *(const uint4*)&P[(size_t)(ibase + srow) * 2048 + k0 + scol];
        uint4 a1 = *(const uint4*)&P[(size_t)(ibase + srow) * 2048 + k0 + scol + 8];
        uint4 b0 = *(const uint4*)&Vt[(size_t)(nbase + srow) * 2048 + k0 + scol];
        uint4 b1 = *(const uint4*)&Vt[(size_t)(nbase + srow) * 2048 + k0 + scol + 8];
        __syncthreads();
        *(uint4*)&As[srow][scol]     = a0;
        *(uint4*)&As[srow][scol + 8] = a1;
        *(uint4*)&Bs[srow][scol]     = b0;
        *(uint4*)&Bs[srow][scol + 8] = b1;
        __syncthreads();

        bf16x8 af[4], bf[4];
#pragma unroll
        for (int m = 0; m < 4; ++m)
            af[m] = *(const bf16x8*)&As[wr * 64 + m * 16 + lrow][kgrp * 8];
#pragma unroll
        for (int n = 0; n < 4; ++n)
            bf[n] = *(const bf16x8*)&Bs[wc * 64 + n * 16 + lrow][kgrp * 8];
#pragma unroll
        for (int m = 0; m < 4; ++m)
#pragma unroll
            for (int n = 0; n < 4; ++n)
                acc[m][n] = __builtin_amdgcn_mfma_f32_16x16x32_bf16(af[m], bf[n], acc[m][n], 0, 0, 0);
    }

#pragma unroll
    for (int m = 0; m < 4; ++m)
#pragma unroll
        for (int n = 0; n < 4; ++n)
#pragma unroll
            for (int r = 0; r < 4; ++r) {
                int gi = ibase + wr * 64 + m * 16 + kgrp * 4 + r;
                int gc = nbase + wc * 64 + n * 16 + lrow;
                O[(size_t)gi * 1024 + gc] = acc[m][n][r];
            }
}

// ---------------------------------------------------------------------------
extern "C" void kernel_launch(void* const* d_in, const int* in_sizes, int n_in,
                              void* d_out, int out_size, void* d_ws, size_t ws_size,
                              hipStream_t stream)
{
    (void)in_sizes; (void)n_in; (void)out_size; (void)ws_size;
    const float* x  = (const float*)d_in[0];
    const float* Wk = (const float*)d_in[1];
    const float* Wq = (const float*)d_in[2];
    const float* Wv = (const float*)d_in[3];
    float* out = (float*)d_out;

    ushort* ws = (ushort*)d_ws;
    ushort* Qb = ws;                                   // 8192*1024
    ushort* Kb = Qb + (size_t)8192 * 1024;             // 8192*1024
    ushort* Vb = Kb + (size_t)8192 * 1024;             // 8192*1024
    ushort* Sb = Vb + (size_t)8192 * 1024;             // 4 * 2048*2048
    ushort* Vt = Sb + (size_t)4 * 2048 * 2048;         // 4 * 1024*2048

    // QKV projection: z=0 -> Wk->Kb, z=1 -> Wq->Qb, z=2 -> Wv->Vb
    qkv_gemm<<<dim3(64, 8, 3), 256, 0, stream>>>(x, Wk, Wq, Wv, Kb, Qb, Vb);

    // scores (triangular tiles), batch-parallel
    scores_gemm<<<dim3(136, 4), 256, 0, stream>>>(Qb, Kb, Sb);

    // softmax in place
    softmax_rows<<<dim3(2048, 4), 256, 0, stream>>>(Sb);

    // V transpose
    transpose_v<<<dim3(64, 32, 4), dim3(32, 32), 0, stream>>>(Vb, Vt);

    // O = P @ V
    pv_gemm<<<dim3(16, 8, 4), 256, 0, stream>>>(Sb, Vt, out);
}

// Round 2
// 195.374 us; speedup vs baseline: 1.2287x; 1.2287x over previous
//
#include <hip/hip_runtime.h>

typedef __attribute__((ext_vector_type(8))) short bf16x8;
typedef __attribute__((ext_vector_type(4))) float f32x4;
typedef __attribute__((ext_vector_type(4))) unsigned short u16x4;
typedef __attribute__((ext_vector_type(8))) unsigned short u16x8;

__device__ __forceinline__ ushort f2bf(float f) {
    unsigned u = __float_as_uint(f);
    unsigned r = (u + 0x7FFFu + ((u >> 16) & 1u)) >> 16;
    return (ushort)r;
}
__device__ __forceinline__ float bf2f(ushort s) {
    return __uint_as_float(((unsigned)s) << 16);
}

// async global->LDS, 16B per lane. LDS dest is wave-uniform base + lane*16.
__device__ __forceinline__ void async16(const ushort* g, ushort* l) {
    __builtin_amdgcn_global_load_lds(
        (const __attribute__((address_space(1))) unsigned*)g,
        (__attribute__((address_space(3))) unsigned*)l, 16, 0, 0);
}

// ---------------------------------------------------------------------------
// Kernel 0: one-time fp32 -> bf16 conversion of x and the three weights.
// xb: 8192*1024, wb: 3*1024*1024 (Wk, Wq, Wv concatenated).
// ---------------------------------------------------------------------------
__global__ __launch_bounds__(256) void cvt_bf16(
    const float* __restrict__ x,
    const float* __restrict__ w0, const float* __restrict__ w1, const float* __restrict__ w2,
    ushort* __restrict__ xb, ushort* __restrict__ wb)
{
    const size_t XN = (size_t)8192 * 1024;
    size_t idx = ((size_t)blockIdx.x * 256 + threadIdx.x) * 8;
    const float* s;
    ushort* d;
    if (idx < XN) { s = x + idx; d = xb + idx; }
    else {
        size_t o = idx - XN;
        int wsel = (int)(o >> 20);
        size_t oo = o & 1048575;
        s = (wsel == 0 ? w0 : wsel == 1 ? w1 : w2) + oo;
        d = wb + o;
    }
    float4 a = *(const float4*)s;
    float4 b = *(const float4*)(s + 4);
    u16x8 p;
    p[0] = f2bf(a.x); p[1] = f2bf(a.y); p[2] = f2bf(a.z); p[3] = f2bf(a.w);
    p[4] = f2bf(b.x); p[5] = f2bf(b.y); p[6] = f2bf(b.z); p[7] = f2bf(b.w);
    *(u16x8*)d = p;
}

// ---------------------------------------------------------------------------
// Shared m97-style GEMM core: 128x128 tile, BK=64, 4 waves (2x2 of 64x64),
// global_load_lds dwordx4 staging, mfma_f32_16x16x32_bf16.
// A, B row-major [rows][K] (B in "B^T" N x K layout).
// ---------------------------------------------------------------------------
__device__ __forceinline__ void mma_tile(
    const ushort* __restrict__ A, int lda, int abase,
    const ushort* __restrict__ B, int ldb, int bbase,
    int ktiles,
    ushort* As, ushort* Bs, f32x4 (&acc)[4][4])
{
    const int tid  = threadIdx.x;
    const int lane = tid & 63, wid = tid >> 6;
    const int wr = wid >> 1, wc = wid & 1;
    const int lrow = lane & 15, kgrp = lane >> 4;
    const int ci = lane >> 3;          // row within 8-row group
    const int cc = (lane & 7) * 8;     // col (bf16 elems)

#pragma unroll
    for (int m = 0; m < 4; ++m)
#pragma unroll
        for (int n = 0; n < 4; ++n) acc[m][n] = (f32x4){0.f, 0.f, 0.f, 0.f};

    for (int kt = 0; kt < ktiles; ++kt) {
        const int k0 = kt * 64;
#pragma unroll
        for (int i = 0; i < 4; ++i) {
            const int r = (wid * 4 + i) * 8 + ci;
            async16(&A[(size_t)(abase + r) * lda + k0 + cc], &As[(wid * 4 + i) * 512]);
            async16(&B[(size_t)(bbase + r) * ldb + k0 + cc], &Bs[(wid * 4 + i) * 512]);
        }
        __syncthreads();
#pragma unroll
        for (int kk = 0; kk < 2; ++kk) {
            bf16x8 af[4], bfr[4];
#pragma unroll
            for (int m = 0; m < 4; ++m)
                af[m] = *(const bf16x8*)&As[(wr * 64 + m * 16 + lrow) * 64 + kk * 32 + kgrp * 8];
#pragma unroll
            for (int n = 0; n < 4; ++n)
                bfr[n] = *(const bf16x8*)&Bs[(wc * 64 + n * 16 + lrow) * 64 + kk * 32 + kgrp * 8];
#pragma unroll
            for (int m = 0; m < 4; ++m)
#pragma unroll
                for (int n = 0; n < 4; ++n)
                    acc[m][n] = __builtin_amdgcn_mfma_f32_16x16x32_bf16(af[m], bfr[n], acc[m][n], 0, 0, 0);
        }
        __syncthreads();
    }
}

// ---------------------------------------------------------------------------
// Kernel 1: QKV projection. xb bf16 [8192][1024], wb bf16 [3][1024][1024]
// (N x K layout). z=0 -> Kb, z=1 -> Qb (row-major), z=2 -> Vt (transposed,
// per-batch [1024][2048]).
// ---------------------------------------------------------------------------
__global__ __launch_bounds__(256) void qkv_gemm(
    const ushort* __restrict__ xb, const ushort* __restrict__ wb,
    ushort* __restrict__ Qb, ushort* __restrict__ Kb, ushort* __restrict__ Vt)
{
    __shared__ ushort As[128 * 64];
    __shared__ ushort Bs[128 * 64];

    const int z = blockIdx.z;
    const ushort* W = wb + (size_t)z * 1024 * 1024;
    const int mbase = blockIdx.x * 128;
    const int nbase = blockIdx.y * 128;

    f32x4 acc[4][4];
    mma_tile(xb, 1024, mbase, W, 1024, nbase, 16, As, Bs, acc);

    const int lane = threadIdx.x & 63, wid = threadIdx.x >> 6;
    const int wr = wid >> 1, wc = wid & 1;
    const int lrow = lane & 15, kgrp = lane >> 4;

    if (z == 2) {
        // write V transposed: Vt[batch][d][s], packed 4 consecutive s per store
        const int b = mbase >> 11;
        const int s0 = mbase & 2047;
        ushort* VtB = Vt + (size_t)b * 1024 * 2048;
#pragma unroll
        for (int m = 0; m < 4; ++m)
#pragma unroll
            for (int n = 0; n < 4; ++n) {
                u16x4 pk;
#pragma unroll
                for (int r = 0; r < 4; ++r) pk[r] = f2bf(acc[m][n][r]);
                const int d = nbase + wc * 64 + n * 16 + lrow;
                const int s = s0 + wr * 64 + m * 16 + kgrp * 4;
                *(u16x4*)&VtB[(size_t)d * 2048 + s] = pk;
            }
    } else {
        ushort* Y = (z == 0) ? Kb : Qb;
#pragma unroll
        for (int m = 0; m < 4; ++m)
#pragma unroll
            for (int n = 0; n < 4; ++n)
#pragma unroll
                for (int r = 0; r < 4; ++r) {
                    const int gr = mbase + wr * 64 + m * 16 + kgrp * 4 + r;
                    const int gc = nbase + wc * 64 + n * 16 + lrow;
                    Y[(size_t)gr * 1024 + gc] = f2bf(acc[m][n][r]);
                }
    }
}

// ---------------------------------------------------------------------------
// Kernel 2: scores S = (Q @ K^T) / 32, lower-triangular 128x128 tiles only.
// ---------------------------------------------------------------------------
__global__ __launch_bounds__(256) void scores_gemm(
    const ushort* __restrict__ Qall, const ushort* __restrict__ Kall,
    ushort* __restrict__ Sall)
{
    __shared__ ushort As[128 * 64];
    __shared__ ushort Bs[128 * 64];

    const ushort* Q = Qall + (size_t)blockIdx.y * 2048 * 1024;
    const ushort* K = Kall + (size_t)blockIdx.y * 2048 * 1024;
    ushort*       S = Sall + (size_t)blockIdx.y * 2048 * 2048;

    int t = blockIdx.x;
    int it = (int)((sqrtf(8.0f * (float)t + 1.0f) - 1.0f) * 0.5f);
    while ((it + 1) * (it + 2) / 2 <= t) ++it;
    while (it * (it + 1) / 2 > t) --it;
    const int jt = t - it * (it + 1) / 2;
    const int ibase = it * 128, jbase = jt * 128;

    f32x4 acc[4][4];
    mma_tile(Q, 1024, ibase, K, 1024, jbase, 16, As, Bs, acc);

    const int lane = threadIdx.x & 63, wid = threadIdx.x >> 6;
    const int wr = wid >> 1, wc = wid & 1;
    const int lrow = lane & 15, kgrp = lane >> 4;
#pragma unroll
    for (int m = 0; m < 4; ++m)
#pragma unroll
        for (int n = 0; n < 4; ++n)
#pragma unroll
            for (int r = 0; r < 4; ++r) {
                const int gi = ibase + wr * 64 + m * 16 + kgrp * 4 + r;
                const int gj = jbase + wc * 64 + n * 16 + lrow;
                S[(size_t)gi * 2048 + gj] = f2bf(acc[m][n][r] * 0.03125f);
            }
}

// ---------------------------------------------------------------------------
// Kernel 3: causal row softmax in place on bf16 S. One block per row.
// Skips loads for fully-masked chunks; writes zeros there (PV reads dense).
// ---------------------------------------------------------------------------
__global__ __launch_bounds__(256) void softmax_rows(ushort* __restrict__ Sall)
{
    ushort* S = Sall + (size_t)blockIdx.y * 2048 * 2048;
    const int i   = blockIdx.x;
    const int tid = threadIdx.x;
    const int j0  = tid * 8;

    union { uint4 v; ushort u[8]; } pk;
    const bool anyvalid = (j0 <= i);
    if (anyvalid) pk.v = *(const uint4*)&S[(size_t)i * 2048 + j0];

    float f[8];
    float mx = -INFINITY;
#pragma unroll
    for (int e = 0; e < 8; ++e) {
        float v = (anyvalid && (j0 + e <= i)) ? bf2f(pk.u[e]) : -INFINITY;
        f[e] = v;
        mx = fmaxf(mx, v);
    }
#pragma unroll
    for (int off = 1; off < 64; off <<= 1) mx = fmaxf(mx, __shfl_xor(mx, off));
    __shared__ float redm[4];
    if ((tid & 63) == 0) redm[tid >> 6] = mx;
    __syncthreads();
    mx = fmaxf(fmaxf(redm[0], redm[1]), fmaxf(redm[2], redm[3]));

    float s = 0.f;
#pragma unroll
    for (int e = 0; e < 8; ++e) {
        float p = __expf(f[e] - mx);
        f[e] = p;
        s += p;
    }
#pragma unroll
    for (int off = 1; off < 64; off <<= 1) s += __shfl_xor(s, off);
    __shared__ float reds[4];
    if ((tid & 63) == 0) reds[tid >> 6] = s;
    __syncthreads();
    s = reds[0] + reds[1] + reds[2] + reds[3];

    const float inv = 1.0f / s;
#pragma unroll
    for (int e = 0; e < 8; ++e) pk.u[e] = f2bf(f[e] * inv);
    *(uint4*)&S[(size_t)i * 2048 + j0] = pk.v;
}

// ---------------------------------------------------------------------------
// Kernel 4: O = P @ V. P bf16 [2048][2048] (upper triangle zeroed),
// Vt bf16 [1024][2048] per batch. K-loop truncated at diagonal. fp32 out.
// Heaviest row-tiles dispatched first (it = 15 - bx).
// ---------------------------------------------------------------------------
__global__ __launch_bounds__(256) void pv_gemm(
    const ushort* __restrict__ Pall, const ushort* __restrict__ Vtall,
    float* __restrict__ Oall)
{
    __shared__ ushort As[128 * 64];
    __shared__ ushort Bs[128 * 64];

    const ushort* P  = Pall  + (size_t)blockIdx.z * 2048 * 2048;
    const ushort* Vt = Vtall + (size_t)blockIdx.z * 1024 * 2048;
    float*        O  = Oall  + (size_t)blockIdx.z * 2048 * 1024;

    const int it = 15 - blockIdx.x;
    const int ibase = it * 128;
    const int nbase = blockIdx.y * 128;
    const int ktiles = 2 * (it + 1);

    f32x4 acc[4][4];
    mma_tile(P, 2048, ibase, Vt, 2048, nbase, ktiles, As, Bs, acc);

    const int lane = threadIdx.x & 63, wid = threadIdx.x >> 6;
    const int wr = wid >> 1, wc = wid & 1;
    const int lrow = lane & 15, kgrp = lane >> 4;
#pragma unroll
    for (int m = 0; m < 4; ++m)
#pragma unroll
        for (int n = 0; n < 4; ++n)
#pragma unroll
            for (int r = 0; r < 4; ++r) {
                const int gi = ibase + wr * 64 + m * 16 + kgrp * 4 + r;
                const int gc = nbase + wc * 64 + n * 16 + lrow;
                O[(size_t)gi * 1024 + gc] = acc[m][n][r];
            }
}

// ---------------------------------------------------------------------------
extern "C" void kernel_launch(void* const* d_in, const int* in_sizes, int n_in,
                              void* d_out, int out_size, void* d_ws, size_t ws_size,
                              hipStream_t stream)
{
    (void)in_sizes; (void)n_in; (void)out_size; (void)ws_size;
    const float* x  = (const float*)d_in[0];
    const float* Wk = (const float*)d_in[1];
    const float* Wq = (const float*)d_in[2];
    const float* Wv = (const float*)d_in[3];
    float* out = (float*)d_out;

    ushort* ws = (ushort*)d_ws;
    ushort* Qb = ws;                                   // 8192*1024
    ushort* Kb = Qb + (size_t)8192 * 1024;             // 8192*1024
    ushort* Sb = Kb + (size_t)8192 * 1024;             // 4*2048*2048
    ushort* Vt = Sb + (size_t)4 * 2048 * 2048;         // 4*1024*2048
    // xb/wb live inside the S region (dead before scores_gemm writes S)
    ushort* xb = Sb;                                   // 8192*1024
    ushort* wb = Sb + (size_t)8192 * 1024;             // 3*1024*1024

    // 0) convert inputs to bf16
    cvt_bf16<<<5632, 256, 0, stream>>>(x, Wk, Wq, Wv, xb, wb);

    // 1) QKV projection (z=0 Wk->Kb, z=1 Wq->Qb, z=2 Wv->Vt transposed)
    qkv_gemm<<<dim3(64, 8, 3), 256, 0, stream>>>(xb, wb, Qb, Kb, Vt);

    // 2) scores, lower-triangular tiles, batch-parallel
    scores_gemm<<<dim3(136, 4), 256, 0, stream>>>(Qb, Kb, Sb);

    // 3) softmax in place
    softmax_rows<<<dim3(2048, 4), 256, 0, stream>>>(Sb);

    // 4) O = P @ V
    pv_gemm<<<dim3(16, 8, 4), 256, 0, stream>>>(Sb, Vt, out);
}